// Round 20
// baseline (73.736 us; speedup 1.0000x reference)
//
#include <hip/hip_runtime.h>
#include <hip/hip_bf16.h>

// B=16, Ci=16, Co=16, H=W=24, hidden=64.
// kt:    K[dy47][dxi][o][i] bf16; dy47 = dy+23 in [0,47), dxi = dx+24 in [0,49).
//        dxi stride = 256 shorts.
// vpad2: bf16 [y'=40][x'=40][b=16][i=16], y'=h+8, x'=w+8, zero halo.
// r20 = r12 conv + LAST-BLOCK COMBINE (3 kernels -> 2): after part write each
//   (wt,hg,oct) block tickets a counter; the 7th combines its 4x4 patch
//   (fixed-order octet sum -> deterministic). 36 atomics total (r13 lesson:
//   per-element atomics serialized). No coop sync (r14). Counters zeroed by
//   prep each call (graph-replay safe).

typedef __attribute__((ext_vector_type(8))) short bf16x8;
typedef __attribute__((ext_vector_type(4))) float f32x4;

#define KT_ELEMS (47*49*256)          // 589,568 bf16
#define VPAD2_ELEMS (40*40*256)       // 409,600 bf16
#define NROWS (47*49)                 // 2303 MLP rows
#define NPOS 576                      // 24*24 output positions
#define NOCT 7                        // dy octets (7*4 = 28 >= 27)
#define PREP_BUILD_BLOCKS 288         // ceil(2303/8)
#define PREP_PAD_BLOCKS (VPAD2_ELEMS/256)   // 1600

// ---------------- Kernel 1: prep = build kt + pad v + zero tickets ----------
__launch_bounds__(256)
__global__ void prep(const float* __restrict__ v,
                     const float* __restrict__ w1, const float* __restrict__ b1,
                     const float* __restrict__ w2, const float* __restrict__ b2,
                     __hip_bfloat16* __restrict__ kt, __hip_bfloat16* __restrict__ vpad,
                     int* __restrict__ tickets)
{
    const int tid = threadIdx.x;

    if (blockIdx.x >= PREP_BUILD_BLOCKS) {
        // ---- pad part: vpad2[y][x][b][i] ----
        int idx = (blockIdx.x - PREP_BUILD_BLOCKS)*256 + tid;
        if (idx >= VPAD2_ELEMS) return;
        int i = idx & 15;
        int b = (idx >> 4) & 15;
        int s = idx >> 8;             // y*40 + x
        int x = s % 40;
        int y = s / 40;
        int h = y - 8, w = x - 8;
        float val = 0.0f;
        if (h >= 0 && h < 24 && w >= 0 && w < 24)
            val = v[((b*16 + i)*24 + h)*24 + w];
        vpad[idx] = __float2bfloat16(val);
        return;
    }

    if (blockIdx.x == 0 && tid < 36) tickets[tid] = 0;   // zero each call

    // ---- build part: 8 rows of the [2303 x 256] K GEMM per block ----
    __shared__ float ty_s[47];
    __shared__ float tx_s[49];
    __shared__ float hid_s[8][64];
    const int r0 = blockIdx.x * 8;

    if (tid < 47)               ty_s[tid]      = tanhf((float)(tid - 23) * (1.0f/6.0f));
    if (tid >= 64 && tid < 113) tx_s[tid - 64] = tanhf((float)(tid - 64 - 24) * (1.0f/6.0f));
    __syncthreads();

    #pragma unroll
    for (int k = 0; k < 2; ++k) {
        int idx = k*256 + tid;
        int rr  = idx >> 6;
        int j   = idx & 63;
        int r   = r0 + rr;
        if (r >= NROWS) r = NROWS - 1;
        int dy47 = r / 49;
        int dxi  = r % 49;
        float x = ty_s[dy47]*w1[2*j] + tx_s[dxi]*w1[2*j+1] + b1[j];
        hid_s[rr][j] = 0.5f*x*(1.0f + erff(x*0.70710678118f));
    }
    __syncthreads();

    const int c = tid;
    float acc[8];
    const float bb = b2[c];
    #pragma unroll
    for (int r = 0; r < 8; ++r) acc[r] = bb;

    const float4* w2v = (const float4*)w2;
    #pragma unroll
    for (int jv = 0; jv < 16; ++jv) {
        float4 wv = w2v[c*16 + jv];
        #pragma unroll
        for (int e = 0; e < 4; ++e) {
            float we = ((const float*)&wv)[e];
            int j = jv*4 + e;
            #pragma unroll
            for (int r = 0; r < 8; ++r)
                acc[r] += hid_s[r][j] * we;
        }
    }

    #pragma unroll
    for (int rr = 0; rr < 8; ++rr) {
        int r = r0 + rr;
        if (r >= NROWS) break;
        kt[r*256 + c] = __float2bfloat16(acc[rr]);
    }
}

// ---------------- Kernel 2: MFMA conv + last-block combine ------------------
// grid (wt6, hg6, oct7), 512 thr = 8 waves = (tq 0..3) x (hhh 0..1).
// A(ww,dxp): dxi = 24 - w0 - ww + 2*dxp + d; dxi stride = 256 shorts.
__launch_bounds__(512)
__global__ void conv_fused(const __hip_bfloat16* __restrict__ kt_,
                           const __hip_bfloat16* __restrict__ vpad_,
                           const float* __restrict__ bias,
                           float* __restrict__ part,
                           int* __restrict__ tickets,
                           float* __restrict__ out)
{
    __shared__ f32x4 red[8][4][64];   // 32 KB; reused as sbuf by last block
    __shared__ int lastFlag;
    const short* kt = (const short*)kt_;
    const short* vp = (const short*)vpad_;

    const int wt  = blockIdx.x;       // 0..5  -> w0 = wt*4
    const int hg  = blockIdx.y;       // 0..5  -> h0 = hg*4
    const int oct = blockIdx.z;       // 0..6
    const int w0  = wt * 4;
    const int h0  = hg * 4;

    const int tid  = threadIdx.x;
    const int lane = tid & 63;
    const int wv   = tid >> 6;        // 0..7
    const int tq   = wv & 3;
    const int hhh  = wv >> 2;         // h-pair of this wave
    const int n    = lane & 15;       // A: o row; B: b col
    const int g    = lane >> 4;       // k-group
    const int d    = g >> 1;          // dx sub-offset within pair
    const int ih   = (g & 1) * 8;     // i-half

    const int t = oct*4 + tq;         // dy index; dy = t - h0 - 3, valid t < 27

    f32x4 acc[2][4];
    #pragma unroll
    for (int hh = 0; hh < 2; ++hh)
        #pragma unroll
        for (int ww = 0; ww < 4; ++ww) acc[hh][ww] = (f32x4){0.f,0.f,0.f,0.f};

    if (t < 27) {
        const int dy47 = t - h0 + 20;                       // in [0,46]
        const short* apb = kt + ((long)(dy47*49 + (24 - w0 + d)))*256 + n*16 + ih;
        const short* bpb = vp + ((long)((t + hhh*2 + 5)*40 + (8 + d)))*256 + n*16 + ih;

        bf16x8 av[4];
        av[0] = *(const bf16x8*)(apb);            // ww=0: dxi base
        av[1] = *(const bf16x8*)(apb - 256);      // ww=1
        av[2] = *(const bf16x8*)(apb - 512);      // ww=2
        av[3] = *(const bf16x8*)(apb - 768);      // ww=3

        #pragma unroll
        for (int dxp = 0; dxp < 12; ++dxp) {
            bf16x8 bv0 = *(const bf16x8*)(bpb +         dxp*512);   // x' += 2/dxp
            bf16x8 bv1 = *(const bf16x8*)(bpb + 10240 + dxp*512);   // +1 y' row
            #pragma unroll
            for (int ww = 0; ww < 4; ++ww) {
                acc[0][ww] = __builtin_amdgcn_mfma_f32_16x16x32_bf16(av[ww], bv0, acc[0][ww], 0, 0, 0);
                acc[1][ww] = __builtin_amdgcn_mfma_f32_16x16x32_bf16(av[ww], bv1, acc[1][ww], 0, 0, 0);
            }
            if (dxp < 11) {
                av[2] = av[0];                    // A(2,dxp+1) = A(0,dxp)
                av[3] = av[1];                    // A(3,dxp+1) = A(1,dxp)
                av[0] = *(const bf16x8*)(apb + (2*dxp + 2)*256);
                av[1] = *(const bf16x8*)(apb + (2*dxp + 1)*256);
            }
        }
    }

    // Two-phase reduce (32 KB): phase hh stores acc[hh][*], wave wv writes
    // part row h = h0 + (wv>>2)*2 + hh.
    #pragma unroll
    for (int hh = 0; hh < 2; ++hh) {
        if (hh) __syncthreads();                  // protect red reuse
        #pragma unroll
        for (int ww = 0; ww < 4; ++ww) red[wv][ww][lane] = acc[hh][ww];
        __syncthreads();

        const int hhh2 = wv >> 2;
        const int ww2  = wv & 3;
        f32x4 s = red[4*hhh2 + 0][ww2][lane];
        s += red[4*hhh2 + 1][ww2][lane];
        s += red[4*hhh2 + 2][ww2][lane];
        s += red[4*hhh2 + 3][ww2][lane];

        const int h = h0 + hhh2*2 + hh;
        const int w = w0 + ww2;
        const int p = h*24 + w;
        float* dst = part + ((size_t)oct*NPOS + p)*256 + (n*16 + g*4);
        *(f32x4*)dst = s;
    }

    // ---- last-block combine for this (wt,hg) group ----
    __syncthreads();                  // all part stores issued
    __threadfence();                  // device-visible before ticket
    __syncthreads();
    if (tid == 0) {
        int tk = atomicAdd(&tickets[hg*6 + wt], 1);
        lastFlag = (tk == NOCT - 1);
    }
    __syncthreads();
    if (!lastFlag) return;
    __threadfence();                  // acquire: see other blocks' part stores

    float* sbuf = (float*)red;        // [16 pos][256 c2] = 16 KB
    const int c2 = tid & 255;
    const int ph2 = tid >> 8;         // p-half
    #pragma unroll
    for (int pl = 0; pl < 8; ++pl) {
        int pos = ph2*8 + pl;         // 0..15: hl = pos>>2, wl = pos&3
        int p = (h0 + (pos >> 2))*24 + (w0 + (pos & 3));
        float s = 0.f;
        #pragma unroll
        for (int oc = 0; oc < NOCT; ++oc)
            s += part[((size_t)oc*NPOS + p)*256 + c2];
        sbuf[pos*256 + c2] = s;
    }
    __syncthreads();

    const float sc = 1.0f/576.0f;
    #pragma unroll
    for (int it = 0; it < 2; ++it) {
        int q   = it*512 + tid;       // 0..1023: c2v = q&255, hl = q>>8
        int c2v = q & 255;
        int hl  = q >> 8;             // it0: 0..1, it1: 2..3
        const float bb = bias[c2v & 15];
        float4 o;
        o.x = sbuf[(hl*4 + 0)*256 + c2v]*sc + bb;
        o.y = sbuf[(hl*4 + 1)*256 + c2v]*sc + bb;
        o.z = sbuf[(hl*4 + 2)*256 + c2v]*sc + bb;
        o.w = sbuf[(hl*4 + 3)*256 + c2v]*sc + bb;
        *(float4*)(out + (size_t)c2v*576 + (h0 + hl)*24 + w0) = o;
    }
}

extern "C" void kernel_launch(void* const* d_in, const int* in_sizes, int n_in,
                              void* d_out, int out_size, void* d_ws, size_t ws_size,
                              hipStream_t stream)
{
    const float* v    = (const float*)d_in[0];
    const float* w1   = (const float*)d_in[1];
    const float* b1   = (const float*)d_in[2];
    const float* w2   = (const float*)d_in[3];
    const float* b2   = (const float*)d_in[4];
    const float* bias = (const float*)d_in[5];
    float* out = (float*)d_out;

    char* ws = (char*)d_ws;
    __hip_bfloat16* kt   = (__hip_bfloat16*)ws;                          // 1,179,136 B
    __hip_bfloat16* vpad = (__hip_bfloat16*)(ws + (size_t)KT_ELEMS*2);   //   819,200 B
    float* part = (float*)(ws + (size_t)KT_ELEMS*2 + (size_t)VPAD2_ELEMS*2); // 4,128,768 B
    int* tickets = (int*)(ws + (size_t)KT_ELEMS*2 + (size_t)VPAD2_ELEMS*2
                             + (size_t)NOCT*NPOS*256*4);                 // 144 B

    prep<<<dim3(PREP_BUILD_BLOCKS + PREP_PAD_BLOCKS), dim3(256), 0, stream>>>(
        v, w1, b1, w2, b2, kt, vpad, tickets);
    conv_fused<<<dim3(6, 6, NOCT), dim3(512), 0, stream>>>(
        kt, vpad, bias, part, tickets, out);
}

// Round 21
// 24.649 us; speedup vs baseline: 2.9915x; 2.9915x over previous
//
#include <hip/hip_runtime.h>
#include <hip/hip_bf16.h>

// B=16, Ci=16, Co=16, H=W=24, hidden=64.
// kt:    K[dy47][dxi][o][i] bf16; dy47 = dy+23 in [0,47), dxi = dx+24 in [0,49).
//        dxi stride = 256 shorts.
// vpad2: bf16 [y'=40][x'=40][b=16][i=16], y'=h+8, x'=w+8, zero halo.
// r21 = r12 with conv occupancy doubled: h-pair split moved wave->grid.
//   Grid (wt6, hg2 12, oct7) = 504 blocks (2/CU = 4 waves/SIMD, vs r12's 2).
//   Waves = tq4 x dxh2 (dx-halves, 6 dxp each). Per-wave sliding-A unchanged.
//   Block rows h0=hg2*2 +{0,1}; dy = ts - h0 - 1, ts = oct*4+tq < 25;
//   dy47 = ts - h0 + 22 in [0,46]; y' = ts + hh + 7 in [7,32] (halo-zero edges).
//   Lessons: no atomics (r13), no coop sync (r14), no device fences (r20),
//   sliding-A 0.5 loads/MFMA (r18), part-buffer 3-kernel pipeline (r12).

typedef __attribute__((ext_vector_type(8))) short bf16x8;
typedef __attribute__((ext_vector_type(4))) float f32x4;

#define KT_ELEMS (47*49*256)          // 589,568 bf16
#define VPAD2_ELEMS (40*40*256)       // 409,600 bf16
#define NROWS (47*49)                 // 2303 MLP rows
#define NPOS 576                      // 24*24 output positions
#define NOCT 7                        // dy octets (7*4 = 28 >= 25)
#define PREP_BUILD_BLOCKS 288         // ceil(2303/8)
#define PREP_PAD_BLOCKS (VPAD2_ELEMS/256)   // 1600

// ---------------- Kernel 1: prep = build K table + pad v (fused grid) -------
__launch_bounds__(256)
__global__ void prep(const float* __restrict__ v,
                     const float* __restrict__ w1, const float* __restrict__ b1,
                     const float* __restrict__ w2, const float* __restrict__ b2,
                     __hip_bfloat16* __restrict__ kt, __hip_bfloat16* __restrict__ vpad)
{
    const int tid = threadIdx.x;

    if (blockIdx.x >= PREP_BUILD_BLOCKS) {
        // ---- pad part: vpad2[y][x][b][i] ----
        int idx = (blockIdx.x - PREP_BUILD_BLOCKS)*256 + tid;
        if (idx >= VPAD2_ELEMS) return;
        int i = idx & 15;
        int b = (idx >> 4) & 15;
        int s = idx >> 8;             // y*40 + x
        int x = s % 40;
        int y = s / 40;
        int h = y - 8, w = x - 8;
        float val = 0.0f;
        if (h >= 0 && h < 24 && w >= 0 && w < 24)
            val = v[((b*16 + i)*24 + h)*24 + w];
        vpad[idx] = __float2bfloat16(val);
        return;
    }

    // ---- build part: 8 rows of the [2303 x 256] K GEMM per block ----
    __shared__ float ty_s[47];
    __shared__ float tx_s[49];
    __shared__ float hid_s[8][64];
    const int r0 = blockIdx.x * 8;

    if (tid < 47)               ty_s[tid]      = tanhf((float)(tid - 23) * (1.0f/6.0f));
    if (tid >= 64 && tid < 113) tx_s[tid - 64] = tanhf((float)(tid - 64 - 24) * (1.0f/6.0f));
    __syncthreads();

    #pragma unroll
    for (int k = 0; k < 2; ++k) {
        int idx = k*256 + tid;
        int rr  = idx >> 6;
        int j   = idx & 63;
        int r   = r0 + rr;
        if (r >= NROWS) r = NROWS - 1;
        int dy47 = r / 49;
        int dxi  = r % 49;
        float x = ty_s[dy47]*w1[2*j] + tx_s[dxi]*w1[2*j+1] + b1[j];
        hid_s[rr][j] = 0.5f*x*(1.0f + erff(x*0.70710678118f));
    }
    __syncthreads();

    const int c = tid;
    float acc[8];
    const float bb = b2[c];
    #pragma unroll
    for (int r = 0; r < 8; ++r) acc[r] = bb;

    const float4* w2v = (const float4*)w2;
    #pragma unroll
    for (int jv = 0; jv < 16; ++jv) {
        float4 wv = w2v[c*16 + jv];
        #pragma unroll
        for (int e = 0; e < 4; ++e) {
            float we = ((const float*)&wv)[e];
            int j = jv*4 + e;
            #pragma unroll
            for (int r = 0; r < 8; ++r)
                acc[r] += hid_s[r][j] * we;
        }
    }

    #pragma unroll
    for (int rr = 0; rr < 8; ++rr) {
        int r = r0 + rr;
        if (r >= NROWS) break;
        kt[r*256 + c] = __float2bfloat16(acc[rr]);
    }
}

// ---------------- Kernel 2: MFMA conv (504 blocks, 4 waves/SIMD) ------------
// Waves: wv = tq + 4*dxh. Wave: one dy (ts = oct*4+tq, valid ts<25), rows
// h0, h0+1, cols w0..w0+3, dxp in [6*dxh, 6*dxh+6). Sliding A: 2 fresh/step.
// A(ww,dxp): dxi = 24 - w0 - ww + 2*dxp + d in [1,47]. B: y'=ts+hh+7 in [7,32].
__launch_bounds__(512)
__global__ void conv_part(const __hip_bfloat16* __restrict__ kt_,
                          const __hip_bfloat16* __restrict__ vpad_,
                          float* __restrict__ part)
{
    __shared__ f32x4 red[8][4][64];   // [src wave][ww][lane], 32 KB
    const short* kt = (const short*)kt_;
    const short* vp = (const short*)vpad_;

    const int wt  = blockIdx.x;       // 0..5  -> w0 = wt*4
    const int hg2 = blockIdx.y;       // 0..11 -> h0 = hg2*2
    const int oct = blockIdx.z;       // 0..6
    const int w0  = wt * 4;
    const int h0  = hg2 * 2;

    const int tid  = threadIdx.x;
    const int lane = tid & 63;
    const int wv   = tid >> 6;        // 0..7
    const int tq   = wv & 3;
    const int dxh  = wv >> 2;         // dx-half: dxp in [6*dxh, 6*dxh+6)
    const int n    = lane & 15;       // A: o row; B: b col
    const int g    = lane >> 4;       // k-group
    const int d    = g >> 1;          // dx sub-offset within pair
    const int ih   = (g & 1) * 8;     // i-half

    const int ts = oct*4 + tq;        // dy = ts - h0 - 1, valid ts < 25

    f32x4 acc[2][4];
    #pragma unroll
    for (int hh = 0; hh < 2; ++hh)
        #pragma unroll
        for (int ww = 0; ww < 4; ++ww) acc[hh][ww] = (f32x4){0.f,0.f,0.f,0.f};

    if (ts < 25) {
        const int dy47 = ts - h0 + 22;                      // in [0,46]
        const short* apb = kt + ((long)(dy47*49 + (24 - w0 + d)))*256 + n*16 + ih;
        // B: y' = ts + hh + 7 in [7,32] < 40; x' = 8 + 2*dxp + d in [8,31]
        const short* bpb = vp + ((long)((ts + 7)*40 + (8 + d)))*256 + n*16 + ih;

        const int dxp0 = dxh*6;
        bf16x8 av[4];
        av[0] = *(const bf16x8*)(apb + (2*dxp0    )*256);   // ww=0
        av[1] = *(const bf16x8*)(apb + (2*dxp0 - 1)*256);   // ww=1
        av[2] = *(const bf16x8*)(apb + (2*dxp0 - 2)*256);   // ww=2
        av[3] = *(const bf16x8*)(apb + (2*dxp0 - 3)*256);   // ww=3

        #pragma unroll
        for (int j = 0; j < 6; ++j) {
            const int dxp = dxp0 + j;
            bf16x8 bv0 = *(const bf16x8*)(bpb +         dxp*512);   // hh=0
            bf16x8 bv1 = *(const bf16x8*)(bpb + 10240 + dxp*512);   // hh=1 (+1 y')
            #pragma unroll
            for (int ww = 0; ww < 4; ++ww) {
                acc[0][ww] = __builtin_amdgcn_mfma_f32_16x16x32_bf16(av[ww], bv0, acc[0][ww], 0, 0, 0);
                acc[1][ww] = __builtin_amdgcn_mfma_f32_16x16x32_bf16(av[ww], bv1, acc[1][ww], 0, 0, 0);
            }
            if (j < 5) {
                av[2] = av[0];                    // A(2,dxp+1) = A(0,dxp)
                av[3] = av[1];                    // A(3,dxp+1) = A(1,dxp)
                av[0] = *(const bf16x8*)(apb + (2*dxp + 2)*256);
                av[1] = *(const bf16x8*)(apb + (2*dxp + 1)*256);
            }
        }
    }

    // Two-phase reduce (32 KB): phase hh stores acc[hh][*]; all 8 waves are
    // slices of the SAME 2x4 output patch -> sum all 8. Writer wave wv<4
    // owns column ww = wv of row h0+hh.
    #pragma unroll
    for (int hh = 0; hh < 2; ++hh) {
        if (hh) __syncthreads();                  // protect red reuse
        #pragma unroll
        for (int ww = 0; ww < 4; ++ww) red[wv][ww][lane] = acc[hh][ww];
        __syncthreads();

        if (wv < 4) {
            f32x4 s = red[0][wv][lane];
            #pragma unroll
            for (int src = 1; src < 8; ++src) s += red[src][wv][lane];

            const int h = h0 + hh;
            const int w = w0 + wv;
            const int p = h*24 + w;
            // part layout: [oct][p][b*16 + o], o = g*4+e contiguous -> f32x4
            float* dst = part + ((size_t)oct*NPOS + p)*256 + (n*16 + g*4);
            *(f32x4*)dst = s;
        }
    }
}

// ---------------- Kernel 3: combine octets + scale + bias (transpose) -------
__launch_bounds__(256)
__global__ void combine(const float* __restrict__ part, const float* __restrict__ bias,
                        float* __restrict__ out)
{
    __shared__ float lds[16][257];
    const int tid = threadIdx.x;
    const int p0  = blockIdx.x * 16;

    #pragma unroll
    for (int pp = 0; pp < 16; ++pp) {
        float s = 0.f;
        #pragma unroll
        for (int oct = 0; oct < NOCT; ++oct)
            s += part[((size_t)oct*NPOS + p0 + pp)*256 + tid];
        lds[pp][tid] = s;
    }
    __syncthreads();

    const int pp = tid & 15;
    const int g  = tid >> 4;          // 0..15 across the block
    const float sc = 1.0f/576.0f;
    #pragma unroll
    for (int cc = 0; cc < 16; ++cc) {
        int c2 = cc*16 + g;           // c2 = b*16 + o
        out[(size_t)c2*576 + p0 + pp] = lds[pp][c2]*sc + bias[c2 & 15];
    }
}

extern "C" void kernel_launch(void* const* d_in, const int* in_sizes, int n_in,
                              void* d_out, int out_size, void* d_ws, size_t ws_size,
                              hipStream_t stream)
{
    const float* v    = (const float*)d_in[0];
    const float* w1   = (const float*)d_in[1];
    const float* b1   = (const float*)d_in[2];
    const float* w2   = (const float*)d_in[3];
    const float* b2   = (const float*)d_in[4];
    const float* bias = (const float*)d_in[5];
    float* out = (float*)d_out;

    char* ws = (char*)d_ws;
    __hip_bfloat16* kt   = (__hip_bfloat16*)ws;                          // 1,179,136 B
    __hip_bfloat16* vpad = (__hip_bfloat16*)(ws + (size_t)KT_ELEMS*2);   //   819,200 B
    float* part = (float*)(ws + (size_t)KT_ELEMS*2 + (size_t)VPAD2_ELEMS*2); // 4,128,768 B

    prep<<<dim3(PREP_BUILD_BLOCKS + PREP_PAD_BLOCKS), dim3(256), 0, stream>>>(
        v, w1, b1, w2, b2, kt, vpad);
    conv_part<<<dim3(6, 12, NOCT), dim3(512), 0, stream>>>(kt, vpad, part);
    combine<<<dim3(NPOS/16), dim3(256), 0, stream>>>(part, bias, out);
}

// Round 22
// 24.586 us; speedup vs baseline: 2.9991x; 1.0025x over previous
//
#include <hip/hip_runtime.h>
#include <hip/hip_bf16.h>

// B=16, Ci=16, Co=16, H=W=24, hidden=64.
// kt:    K[dy47][dxi][o][i] bf16; dy47 = dy+23 in [0,47), dxi = dx+24 in [0,49).
//        dxi stride = 256 shorts.
// vpad2: bf16 [y'=40][x'=40][b=16][i=16], y'=h+8, x'=w+8, zero halo.
// r22 = r21 (best: 24.65us) + slim prep grid: pad = 200 blocks x 8 elem/thread
//   (bf16x8 store; reads stay scattered -- r19 proved L3 absorbs them).
//   conv_part/combine byte-identical to r21 (504 blocks, 4 waves/SIMD).
//   Lessons: no atomics (r13), no coop sync (r14), no device fences (r20),
//   sliding-A 0.5 loads/MFMA (r18), occupancy via grid split (r21).

typedef __attribute__((ext_vector_type(8))) short bf16x8;
typedef __attribute__((ext_vector_type(4))) float f32x4;

#define KT_ELEMS (47*49*256)          // 589,568 bf16
#define VPAD2_ELEMS (40*40*256)       // 409,600 bf16
#define NROWS (47*49)                 // 2303 MLP rows
#define NPOS 576                      // 24*24 output positions
#define NOCT 7                        // dy octets (7*4 = 28 >= 25)
#define PREP_BUILD_BLOCKS 288         // ceil(2303/8)
#define PREP_PAD_BLOCKS 200           // 200 * 256thr * 8elem = 409,600

// ---------------- Kernel 1: prep = build K table + pad v (fused grid) -------
__launch_bounds__(256)
__global__ void prep(const float* __restrict__ v,
                     const float* __restrict__ w1, const float* __restrict__ b1,
                     const float* __restrict__ w2, const float* __restrict__ b2,
                     __hip_bfloat16* __restrict__ kt, __hip_bfloat16* __restrict__ vpad)
{
    const int tid = threadIdx.x;

    if (blockIdx.x >= PREP_BUILD_BLOCKS) {
        // ---- pad: vpad2[y][x][b][i], 8 consecutive elems/thread, 1 bf16x8 store
        int base = ((blockIdx.x - PREP_BUILD_BLOCKS)*256 + tid) * 8;
        int s = base >> 8;            // y*40 + x  (same for all 8 elems)
        int x = s % 40;
        int y = s / 40;
        int h = y - 8, w = x - 8;
        bf16x8 o = {0,0,0,0,0,0,0,0};
        if (h >= 0 && h < 24 && w >= 0 && w < 24) {
            #pragma unroll
            for (int e = 0; e < 8; ++e) {
                int bi = (base & 255) + e;              // b*16 + i
                float val = v[(size_t)bi*576 + h*24 + w];
                __hip_bfloat16 bv = __float2bfloat16(val);
                o[e] = *(short*)&bv;
            }
        }
        *(bf16x8*)((short*)vpad + base) = o;
        return;
    }

    // ---- build part: 8 rows of the [2303 x 256] K GEMM per block ----
    __shared__ float ty_s[47];
    __shared__ float tx_s[49];
    __shared__ float hid_s[8][64];
    const int r0 = blockIdx.x * 8;

    if (tid < 47)               ty_s[tid]      = tanhf((float)(tid - 23) * (1.0f/6.0f));
    if (tid >= 64 && tid < 113) tx_s[tid - 64] = tanhf((float)(tid - 64 - 24) * (1.0f/6.0f));
    __syncthreads();

    #pragma unroll
    for (int k = 0; k < 2; ++k) {
        int idx = k*256 + tid;
        int rr  = idx >> 6;
        int j   = idx & 63;
        int r   = r0 + rr;
        if (r >= NROWS) r = NROWS - 1;
        int dy47 = r / 49;
        int dxi  = r % 49;
        float x = ty_s[dy47]*w1[2*j] + tx_s[dxi]*w1[2*j+1] + b1[j];
        hid_s[rr][j] = 0.5f*x*(1.0f + erff(x*0.70710678118f));
    }
    __syncthreads();

    const int c = tid;
    float acc[8];
    const float bb = b2[c];
    #pragma unroll
    for (int r = 0; r < 8; ++r) acc[r] = bb;

    const float4* w2v = (const float4*)w2;
    #pragma unroll
    for (int jv = 0; jv < 16; ++jv) {
        float4 wv = w2v[c*16 + jv];
        #pragma unroll
        for (int e = 0; e < 4; ++e) {
            float we = ((const float*)&wv)[e];
            int j = jv*4 + e;
            #pragma unroll
            for (int r = 0; r < 8; ++r)
                acc[r] += hid_s[r][j] * we;
        }
    }

    #pragma unroll
    for (int rr = 0; rr < 8; ++rr) {
        int r = r0 + rr;
        if (r >= NROWS) break;
        kt[r*256 + c] = __float2bfloat16(acc[rr]);
    }
}

// ---------------- Kernel 2: MFMA conv (byte-identical to r21) ---------------
// grid (wt6, hg2 12, oct7) = 504 blocks, 8 waves = tq4 x dxh2.
// A(ww,dxp): dxi = 24 - w0 - ww + 2*dxp + d in [1,47]; dy47 = ts - h0 + 22.
__launch_bounds__(512)
__global__ void conv_part(const __hip_bfloat16* __restrict__ kt_,
                          const __hip_bfloat16* __restrict__ vpad_,
                          float* __restrict__ part)
{
    __shared__ f32x4 red[8][4][64];   // [src wave][ww][lane], 32 KB
    const short* kt = (const short*)kt_;
    const short* vp = (const short*)vpad_;

    const int wt  = blockIdx.x;       // 0..5  -> w0 = wt*4
    const int hg2 = blockIdx.y;       // 0..11 -> h0 = hg2*2
    const int oct = blockIdx.z;       // 0..6
    const int w0  = wt * 4;
    const int h0  = hg2 * 2;

    const int tid  = threadIdx.x;
    const int lane = tid & 63;
    const int wv   = tid >> 6;        // 0..7
    const int tq   = wv & 3;
    const int dxh  = wv >> 2;         // dx-half: dxp in [6*dxh, 6*dxh+6)
    const int n    = lane & 15;       // A: o row; B: b col
    const int g    = lane >> 4;       // k-group
    const int d    = g >> 1;          // dx sub-offset within pair
    const int ih   = (g & 1) * 8;     // i-half

    const int ts = oct*4 + tq;        // dy = ts - h0 - 1, valid ts < 25

    f32x4 acc[2][4];
    #pragma unroll
    for (int hh = 0; hh < 2; ++hh)
        #pragma unroll
        for (int ww = 0; ww < 4; ++ww) acc[hh][ww] = (f32x4){0.f,0.f,0.f,0.f};

    if (ts < 25) {
        const int dy47 = ts - h0 + 22;                      // in [0,46]
        const short* apb = kt + ((long)(dy47*49 + (24 - w0 + d)))*256 + n*16 + ih;
        // B: y' = ts + hh + 7 in [7,32] < 40; x' = 8 + 2*dxp + d in [8,31]
        const short* bpb = vp + ((long)((ts + 7)*40 + (8 + d)))*256 + n*16 + ih;

        const int dxp0 = dxh*6;
        bf16x8 av[4];
        av[0] = *(const bf16x8*)(apb + (2*dxp0    )*256);   // ww=0
        av[1] = *(const bf16x8*)(apb + (2*dxp0 - 1)*256);   // ww=1
        av[2] = *(const bf16x8*)(apb + (2*dxp0 - 2)*256);   // ww=2
        av[3] = *(const bf16x8*)(apb + (2*dxp0 - 3)*256);   // ww=3

        #pragma unroll
        for (int j = 0; j < 6; ++j) {
            const int dxp = dxp0 + j;
            bf16x8 bv0 = *(const bf16x8*)(bpb +         dxp*512);   // hh=0
            bf16x8 bv1 = *(const bf16x8*)(bpb + 10240 + dxp*512);   // hh=1 (+1 y')
            #pragma unroll
            for (int ww = 0; ww < 4; ++ww) {
                acc[0][ww] = __builtin_amdgcn_mfma_f32_16x16x32_bf16(av[ww], bv0, acc[0][ww], 0, 0, 0);
                acc[1][ww] = __builtin_amdgcn_mfma_f32_16x16x32_bf16(av[ww], bv1, acc[1][ww], 0, 0, 0);
            }
            if (j < 5) {
                av[2] = av[0];                    // A(2,dxp+1) = A(0,dxp)
                av[3] = av[1];                    // A(3,dxp+1) = A(1,dxp)
                av[0] = *(const bf16x8*)(apb + (2*dxp + 2)*256);
                av[1] = *(const bf16x8*)(apb + (2*dxp + 1)*256);
            }
        }
    }

    // Two-phase reduce: all 8 waves hold slices of the SAME 2x4 patch.
    #pragma unroll
    for (int hh = 0; hh < 2; ++hh) {
        if (hh) __syncthreads();                  // protect red reuse
        #pragma unroll
        for (int ww = 0; ww < 4; ++ww) red[wv][ww][lane] = acc[hh][ww];
        __syncthreads();

        if (wv < 4) {
            f32x4 s = red[0][wv][lane];
            #pragma unroll
            for (int src = 1; src < 8; ++src) s += red[src][wv][lane];

            const int h = h0 + hh;
            const int w = w0 + wv;
            const int p = h*24 + w;
            // part layout: [oct][p][b*16 + o], o = g*4+e contiguous -> f32x4
            float* dst = part + ((size_t)oct*NPOS + p)*256 + (n*16 + g*4);
            *(f32x4*)dst = s;
        }
    }
}

// ---------------- Kernel 3: combine (byte-identical to r21) -----------------
__launch_bounds__(256)
__global__ void combine(const float* __restrict__ part, const float* __restrict__ bias,
                        float* __restrict__ out)
{
    __shared__ float lds[16][257];
    const int tid = threadIdx.x;
    const int p0  = blockIdx.x * 16;

    #pragma unroll
    for (int pp = 0; pp < 16; ++pp) {
        float s = 0.f;
        #pragma unroll
        for (int oct = 0; oct < NOCT; ++oct)
            s += part[((size_t)oct*NPOS + p0 + pp)*256 + tid];
        lds[pp][tid] = s;
    }
    __syncthreads();

    const int pp = tid & 15;
    const int g  = tid >> 4;          // 0..15 across the block
    const float sc = 1.0f/576.0f;
    #pragma unroll
    for (int cc = 0; cc < 16; ++cc) {
        int c2 = cc*16 + g;           // c2 = b*16 + o
        out[(size_t)c2*576 + p0 + pp] = lds[pp][c2]*sc + bias[c2 & 15];
    }
}

extern "C" void kernel_launch(void* const* d_in, const int* in_sizes, int n_in,
                              void* d_out, int out_size, void* d_ws, size_t ws_size,
                              hipStream_t stream)
{
    const float* v    = (const float*)d_in[0];
    const float* w1   = (const float*)d_in[1];
    const float* b1   = (const float*)d_in[2];
    const float* w2   = (const float*)d_in[3];
    const float* b2   = (const float*)d_in[4];
    const float* bias = (const float*)d_in[5];
    float* out = (float*)d_out;

    char* ws = (char*)d_ws;
    __hip_bfloat16* kt   = (__hip_bfloat16*)ws;                          // 1,179,136 B
    __hip_bfloat16* vpad = (__hip_bfloat16*)(ws + (size_t)KT_ELEMS*2);   //   819,200 B
    float* part = (float*)(ws + (size_t)KT_ELEMS*2 + (size_t)VPAD2_ELEMS*2); // 4,128,768 B

    prep<<<dim3(PREP_BUILD_BLOCKS + PREP_PAD_BLOCKS), dim3(256), 0, stream>>>(
        v, w1, b1, w2, b2, kt, vpad);
    conv_part<<<dim3(6, 12, NOCT), dim3(512), 0, stream>>>(kt, vpad, part);
    combine<<<dim3(NPOS/16), dim3(256), 0, stream>>>(part, bias, out);
}

// Round 24
// 23.640 us; speedup vs baseline: 3.1191x; 1.0400x over previous
//
#include <hip/hip_runtime.h>
#include <hip/hip_bf16.h>

// B=16, Ci=16, Co=16, H=W=24, hidden=64.
// kt:    K[dy47][dxi][o][i] bf16; dy47 = dy+23 in [0,47), dxi = dx+24 in [0,49).
//        dxi stride = 256 shorts.
// vpad2: bf16 [y'=40][x'=40][b=16][i=16], y'=h+8, x'=w+8, zero halo.
// r23 = r22 + bf16 part buffer (8.3 -> 4.1 MB part round trip; error budget:
//   bf16 partial rounding adds ~3.5e-4 after /576, threshold headroom 4x).
//   conv/combine otherwise identical to r21/r22 (504 blocks, 4 waves/SIMD).
//   Lessons: no atomics (r13), no coop sync (r14), no device fences (r20),
//   sliding-A 0.5 loads/MFMA (r18), occupancy via grid split (r21).

typedef __attribute__((ext_vector_type(8))) short bf16x8;
typedef __attribute__((ext_vector_type(4))) float f32x4;

#define KT_ELEMS (47*49*256)          // 589,568 bf16
#define VPAD2_ELEMS (40*40*256)       // 409,600 bf16
#define NROWS (47*49)                 // 2303 MLP rows
#define NPOS 576                      // 24*24 output positions
#define NOCT 7                        // dy octets (7*4 = 28 >= 25)
#define PREP_BUILD_BLOCKS 288         // ceil(2303/8)
#define PREP_PAD_BLOCKS 200           // 200 * 256thr * 8elem = 409,600

// ---------------- Kernel 1: prep = build K table + pad v (fused grid) -------
__launch_bounds__(256)
__global__ void prep(const float* __restrict__ v,
                     const float* __restrict__ w1, const float* __restrict__ b1,
                     const float* __restrict__ w2, const float* __restrict__ b2,
                     __hip_bfloat16* __restrict__ kt, __hip_bfloat16* __restrict__ vpad)
{
    const int tid = threadIdx.x;

    if (blockIdx.x >= PREP_BUILD_BLOCKS) {
        // ---- pad: vpad2[y][x][b][i], 8 consecutive elems/thread, 1 bf16x8 store
        int base = ((blockIdx.x - PREP_BUILD_BLOCKS)*256 + tid) * 8;
        int s = base >> 8;            // y*40 + x  (same for all 8 elems)
        int x = s % 40;
        int y = s / 40;
        int h = y - 8, w = x - 8;
        bf16x8 o = {0,0,0,0,0,0,0,0};
        if (h >= 0 && h < 24 && w >= 0 && w < 24) {
            #pragma unroll
            for (int e = 0; e < 8; ++e) {
                int bi = (base & 255) + e;              // b*16 + i
                float val = v[(size_t)bi*576 + h*24 + w];
                __hip_bfloat16 bv = __float2bfloat16(val);
                o[e] = *(short*)&bv;
            }
        }
        *(bf16x8*)((short*)vpad + base) = o;
        return;
    }

    // ---- build part: 8 rows of the [2303 x 256] K GEMM per block ----
    __shared__ float ty_s[47];
    __shared__ float tx_s[49];
    __shared__ float hid_s[8][64];
    const int r0 = blockIdx.x * 8;

    if (tid < 47)               ty_s[tid]      = tanhf((float)(tid - 23) * (1.0f/6.0f));
    if (tid >= 64 && tid < 113) tx_s[tid - 64] = tanhf((float)(tid - 64 - 24) * (1.0f/6.0f));
    __syncthreads();

    #pragma unroll
    for (int k = 0; k < 2; ++k) {
        int idx = k*256 + tid;
        int rr  = idx >> 6;
        int j   = idx & 63;
        int r   = r0 + rr;
        if (r >= NROWS) r = NROWS - 1;
        int dy47 = r / 49;
        int dxi  = r % 49;
        float x = ty_s[dy47]*w1[2*j] + tx_s[dxi]*w1[2*j+1] + b1[j];
        hid_s[rr][j] = 0.5f*x*(1.0f + erff(x*0.70710678118f));
    }
    __syncthreads();

    const int c = tid;
    float acc[8];
    const float bb = b2[c];
    #pragma unroll
    for (int r = 0; r < 8; ++r) acc[r] = bb;

    const float4* w2v = (const float4*)w2;
    #pragma unroll
    for (int jv = 0; jv < 16; ++jv) {
        float4 wv = w2v[c*16 + jv];
        #pragma unroll
        for (int e = 0; e < 4; ++e) {
            float we = ((const float*)&wv)[e];
            int j = jv*4 + e;
            #pragma unroll
            for (int r = 0; r < 8; ++r)
                acc[r] += hid_s[r][j] * we;
        }
    }

    #pragma unroll
    for (int rr = 0; rr < 8; ++rr) {
        int r = r0 + rr;
        if (r >= NROWS) break;
        kt[r*256 + c] = __float2bfloat16(acc[rr]);
    }
}

// ---------------- Kernel 2: MFMA conv (bf16 partial store) ------------------
// grid (wt6, hg2 12, oct7) = 504 blocks, 8 waves = tq4 x dxh2.
// A(ww,dxp): dxi = 24 - w0 - ww + 2*dxp + d in [1,47]; dy47 = ts - h0 + 22.
__launch_bounds__(512)
__global__ void conv_part(const __hip_bfloat16* __restrict__ kt_,
                          const __hip_bfloat16* __restrict__ vpad_,
                          __hip_bfloat16* __restrict__ part)
{
    __shared__ f32x4 red[8][4][64];   // [src wave][ww][lane], 32 KB
    const short* kt = (const short*)kt_;
    const short* vp = (const short*)vpad_;

    const int wt  = blockIdx.x;       // 0..5  -> w0 = wt*4
    const int hg2 = blockIdx.y;       // 0..11 -> h0 = hg2*2
    const int oct = blockIdx.z;       // 0..6
    const int w0  = wt * 4;
    const int h0  = hg2 * 2;

    const int tid  = threadIdx.x;
    const int lane = tid & 63;
    const int wv   = tid >> 6;        // 0..7
    const int tq   = wv & 3;
    const int dxh  = wv >> 2;         // dx-half: dxp in [6*dxh, 6*dxh+6)
    const int n    = lane & 15;       // A: o row; B: b col
    const int g    = lane >> 4;       // k-group
    const int d    = g >> 1;          // dx sub-offset within pair
    const int ih   = (g & 1) * 8;     // i-half

    const int ts = oct*4 + tq;        // dy = ts - h0 - 1, valid ts < 25

    f32x4 acc[2][4];
    #pragma unroll
    for (int hh = 0; hh < 2; ++hh)
        #pragma unroll
        for (int ww = 0; ww < 4; ++ww) acc[hh][ww] = (f32x4){0.f,0.f,0.f,0.f};

    if (ts < 25) {
        const int dy47 = ts - h0 + 22;                      // in [0,46]
        const short* apb = kt + ((long)(dy47*49 + (24 - w0 + d)))*256 + n*16 + ih;
        // B: y' = ts + hh + 7 in [7,32] < 40; x' = 8 + 2*dxp + d in [8,31]
        const short* bpb = vp + ((long)((ts + 7)*40 + (8 + d)))*256 + n*16 + ih;

        const int dxp0 = dxh*6;
        bf16x8 av[4];
        av[0] = *(const bf16x8*)(apb + (2*dxp0    )*256);   // ww=0
        av[1] = *(const bf16x8*)(apb + (2*dxp0 - 1)*256);   // ww=1
        av[2] = *(const bf16x8*)(apb + (2*dxp0 - 2)*256);   // ww=2
        av[3] = *(const bf16x8*)(apb + (2*dxp0 - 3)*256);   // ww=3

        #pragma unroll
        for (int j = 0; j < 6; ++j) {
            const int dxp = dxp0 + j;
            bf16x8 bv0 = *(const bf16x8*)(bpb +         dxp*512);   // hh=0
            bf16x8 bv1 = *(const bf16x8*)(bpb + 10240 + dxp*512);   // hh=1 (+1 y')
            #pragma unroll
            for (int ww = 0; ww < 4; ++ww) {
                acc[0][ww] = __builtin_amdgcn_mfma_f32_16x16x32_bf16(av[ww], bv0, acc[0][ww], 0, 0, 0);
                acc[1][ww] = __builtin_amdgcn_mfma_f32_16x16x32_bf16(av[ww], bv1, acc[1][ww], 0, 0, 0);
            }
            if (j < 5) {
                av[2] = av[0];                    // A(2,dxp+1) = A(0,dxp)
                av[3] = av[1];                    // A(3,dxp+1) = A(1,dxp)
                av[0] = *(const bf16x8*)(apb + (2*dxp + 2)*256);
                av[1] = *(const bf16x8*)(apb + (2*dxp + 1)*256);
            }
        }
    }

    // Two-phase reduce: all 8 waves hold slices of the SAME 2x4 patch.
    #pragma unroll
    for (int hh = 0; hh < 2; ++hh) {
        if (hh) __syncthreads();                  // protect red reuse
        #pragma unroll
        for (int ww = 0; ww < 4; ++ww) red[wv][ww][lane] = acc[hh][ww];
        __syncthreads();

        if (wv < 4) {
            f32x4 s = red[0][wv][lane];
            #pragma unroll
            for (int src = 1; src < 8; ++src) s += red[src][wv][lane];

            const int h = h0 + hh;
            const int w = w0 + wv;
            const int p = h*24 + w;
            // part layout: [oct][p][b*16 + o] bf16, o = g*4+e -> short4 store
            short4 o4;
            __hip_bfloat16 t0 = __float2bfloat16(s[0]); o4.x = *(short*)&t0;
            __hip_bfloat16 t1 = __float2bfloat16(s[1]); o4.y = *(short*)&t1;
            __hip_bfloat16 t2 = __float2bfloat16(s[2]); o4.z = *(short*)&t2;
            __hip_bfloat16 t3 = __float2bfloat16(s[3]); o4.w = *(short*)&t3;
            short* dst = (short*)part + ((size_t)oct*NPOS + p)*256 + (n*16 + g*4);
            *(short4*)dst = o4;
        }
    }
}

// ---------------- Kernel 3: combine octets + scale + bias (transpose) -------
__launch_bounds__(256)
__global__ void combine(const __hip_bfloat16* __restrict__ part,
                        const float* __restrict__ bias,
                        float* __restrict__ out)
{
    __shared__ float lds[16][257];
    const int tid = threadIdx.x;
    const int p0  = blockIdx.x * 16;

    #pragma unroll
    for (int pp = 0; pp < 16; ++pp) {
        float s = 0.f;
        #pragma unroll
        for (int oct = 0; oct < NOCT; ++oct)
            s += __bfloat162float(part[((size_t)oct*NPOS + p0 + pp)*256 + tid]);
        lds[pp][tid] = s;
    }
    __syncthreads();

    const int pp = tid & 15;
    const int g  = tid >> 4;          // 0..15 across the block
    const float sc = 1.0f/576.0f;
    #pragma unroll
    for (int cc = 0; cc < 16; ++cc) {
        int c2 = cc*16 + g;           // c2 = b*16 + o
        out[(size_t)c2*576 + p0 + pp] = lds[pp][c2]*sc + bias[c2 & 15];
    }
}

extern "C" void kernel_launch(void* const* d_in, const int* in_sizes, int n_in,
                              void* d_out, int out_size, void* d_ws, size_t ws_size,
                              hipStream_t stream)
{
    const float* v    = (const float*)d_in[0];
    const float* w1   = (const float*)d_in[1];
    const float* b1   = (const float*)d_in[2];
    const float* w2   = (const float*)d_in[3];
    const float* b2   = (const float*)d_in[4];
    const float* bias = (const float*)d_in[5];
    float* out = (float*)d_out;

    char* ws = (char*)d_ws;
    __hip_bfloat16* kt   = (__hip_bfloat16*)ws;                          // 1,179,136 B
    __hip_bfloat16* vpad = (__hip_bfloat16*)(ws + (size_t)KT_ELEMS*2);   //   819,200 B
    __hip_bfloat16* part = (__hip_bfloat16*)(ws + (size_t)KT_ELEMS*2
                                                + (size_t)VPAD2_ELEMS*2); // 2,064,384 B

    prep<<<dim3(PREP_BUILD_BLOCKS + PREP_PAD_BLOCKS), dim3(256), 0, stream>>>(
        v, w1, b1, w2, b2, kt, vpad);
    conv_part<<<dim3(6, 12, NOCT), dim3(512), 0, stream>>>(kt, vpad, part);
    combine<<<dim3(NPOS/16), dim3(256), 0, stream>>>(part, bias, out);
}